// Round 4
// baseline (162.543 us; speedup 1.0000x reference)
//
#include <hip/hip_runtime.h>
#include <math.h>

#define DIM 128
#define PSTRIDE 132          // per-partial floats: l, pad3, acc[128] (16B-aligned acc)
#define NEG_BIG (-3.0e38f)

// ---------------------------------------------------------------------------
// Phase A: logits. 4 lanes per row ("quad"), 16 rows per wave-chunk.
// Lane (quad,rsub) accumulates |k-q| over cols quad*4 + j*16 + e (j=0..7) in
// registers (8 independent float4 loads), then 2 shfl_xor fold the quad.
// Per-instruction footprint: 16 rows x 64B contiguous segments -> coalesced.
// Global max via atomicMin on float bits (logits <= 0 so min-uint == max-f32).
// ---------------------------------------------------------------------------
__global__ __launch_bounds__(256) void nd_logits(const float* __restrict__ query,
                                                 const float* __restrict__ keys,
                                                 float* __restrict__ logits,
                                                 unsigned int* __restrict__ maxbits,
                                                 int nrows, int nchunks, int P) {
    const int tid  = threadIdx.x;
    const int lane = tid & 63;
    const int quad = lane & 3;
    const int rsub = lane >> 2;                       // 0..15
    const int wid  = blockIdx.x * (blockDim.x >> 6) + (tid >> 6);

    float4 qv[8];
    #pragma unroll
    for (int j = 0; j < 8; ++j)
        qv[j] = *reinterpret_cast<const float4*>(query + quad * 4 + j * 16);

    float wmax = NEG_BIG;

    for (int c = wid; c < nchunks; c += P) {
        const int  row = c * 16 + rsub;
        const bool ok  = row < nrows;
        const int  rr  = ok ? row : (nrows - 1);
        const float* kp = keys + (size_t)rr * DIM + quad * 4;
        float s = 0.f;
        #pragma unroll
        for (int j = 0; j < 8; ++j) {
            const float4 k = *reinterpret_cast<const float4*>(kp + j * 16);
            s += fabsf(k.x - qv[j].x) + fabsf(k.y - qv[j].y)
               + fabsf(k.z - qv[j].z) + fabsf(k.w - qv[j].w);
        }
        s += __shfl_xor(s, 1, 64);                    // fold quad: 2 shfl / 16 rows
        s += __shfl_xor(s, 2, 64);
        const float lg = ok ? -s : NEG_BIG;
        wmax = fmaxf(wmax, lg);
        if (quad == 0 && ok) logits[row] = lg;        // 16 dwords, 64B contiguous
    }

    #pragma unroll
    for (int off = 1; off < 64; off <<= 1)
        wmax = fmaxf(wmax, __shfl_xor(wmax, off, 64));
    if (lane == 0) atomicMin(maxbits, __float_as_uint(wmax));
}

// ---------------------------------------------------------------------------
// Phase C: weighted value accumulation with FIXED global max M.
// Same quad layout: lane accumulates acc[8] (its 32 cols) over its rows with
// w = exp(logit[row]-M); end-of-kernel reduce over rsub (off 4..32).
// Pure streaming FMA in the loop: no cross-lane ops, no rescales.
// ---------------------------------------------------------------------------
__global__ __launch_bounds__(256) void nd_accum(const float* __restrict__ values,
                                                const float* __restrict__ logits,
                                                const unsigned int* __restrict__ maxbits,
                                                float* __restrict__ part,
                                                int nrows, int nchunks, int P) {
    const int tid  = threadIdx.x;
    const int lane = tid & 63;
    const int quad = lane & 3;
    const int rsub = lane >> 2;
    const int wid  = blockIdx.x * (blockDim.x >> 6) + (tid >> 6);

    const float M = __uint_as_float(*maxbits);

    float4 acc[8];
    #pragma unroll
    for (int j = 0; j < 8; ++j) acc[j] = make_float4(0.f, 0.f, 0.f, 0.f);
    float l = 0.f;

    for (int c = wid; c < nchunks; c += P) {
        const int  row = c * 16 + rsub;
        const bool ok  = row < nrows;
        const int  rr  = ok ? row : (nrows - 1);
        const float w  = ok ? __expf(logits[rr] - M) : 0.f;
        const float* vp = values + (size_t)rr * DIM + quad * 4;
        l += w;
        #pragma unroll
        for (int j = 0; j < 8; ++j) {
            const float4 v = *reinterpret_cast<const float4*>(vp + j * 16);
            acc[j].x += w * v.x; acc[j].y += w * v.y;
            acc[j].z += w * v.z; acc[j].w += w * v.w;
        }
    }

    // Reduce over rsub (quad fixed): each col summed over all 16 row-subslots.
    #pragma unroll
    for (int off = 4; off < 64; off <<= 1) {
        #pragma unroll
        for (int j = 0; j < 8; ++j) {
            acc[j].x += __shfl_xor(acc[j].x, off, 64);
            acc[j].y += __shfl_xor(acc[j].y, off, 64);
            acc[j].z += __shfl_xor(acc[j].z, off, 64);
            acc[j].w += __shfl_xor(acc[j].w, off, 64);
        }
        l += __shfl_xor(l, off, 64);   // rows counted once (quad-redundant w untouched)
    }

    if (rsub == 0) {                   // lanes 0..3 hold the wave's 128-col partial
        float* wp = part + (size_t)wid * PSTRIDE;
        if (quad == 0) wp[0] = l;
        #pragma unroll
        for (int j = 0; j < 8; ++j)
            *reinterpret_cast<float4*>(wp + 4 + quad * 4 + j * 16) = acc[j];
    }
}

// ---------------------------------------------------------------------------
// Merge 64 consecutive partials into one (plain sums).
// ---------------------------------------------------------------------------
__global__ __launch_bounds__(256) void nd_merge(const float* __restrict__ part,
                                                float* __restrict__ part2) {
    __shared__ float sh_red[256];
    __shared__ float shL;
    const int tid  = threadIdx.x;
    const int base = blockIdx.x * 64;

    if (tid < 64) {
        float lp = part[(size_t)(base + tid) * PSTRIDE];
        #pragma unroll
        for (int off = 32; off > 0; off >>= 1)
            lp += __shfl_xor(lp, off, 64);
        if (tid == 0) shL = lp;
    }

    const int d = tid & 127, g = tid >> 7;
    float o = 0.f;
    for (int p = g; p < 64; p += 2)
        o += part[(size_t)(base + p) * PSTRIDE + 4 + d];
    sh_red[tid] = o;
    __syncthreads();

    if (tid < 128) {
        float* wp = part2 + (size_t)blockIdx.x * PSTRIDE;
        if (tid == 0) wp[0] = shL;
        wp[4 + tid] = sh_red[tid] + sh_red[tid + 128];
    }
}

// ---------------------------------------------------------------------------
// Final: sum the B2 (<=128) level-2 partials, normalize, write out[128].
// ---------------------------------------------------------------------------
__global__ __launch_bounds__(256) void nd_final(const float* __restrict__ part2,
                                                float* __restrict__ out, int B2) {
    __shared__ float sh_red[256];
    __shared__ float shL;
    const int tid = threadIdx.x;

    if (tid < 64) {
        float lp = 0.f;
        for (int p = tid; p < B2; p += 64)
            lp += part2[(size_t)p * PSTRIDE];
        #pragma unroll
        for (int off = 32; off > 0; off >>= 1)
            lp += __shfl_xor(lp, off, 64);
        if (tid == 0) shL = lp;
    }

    const int d = tid & 127, g = tid >> 7;
    float o = 0.f;
    for (int p = g; p < B2; p += 2)
        o += part2[(size_t)p * PSTRIDE + 4 + d];
    sh_red[tid] = o;
    __syncthreads();

    if (tid < 128)
        out[tid] = (sh_red[tid] + sh_red[tid + 128]) / shL;
}

extern "C" void kernel_launch(void* const* d_in, const int* in_sizes, int n_in,
                              void* d_out, int out_size, void* d_ws, size_t ws_size,
                              hipStream_t stream) {
    const float* query  = (const float*)d_in[0];
    const float* keys   = (const float*)d_in[1];
    const float* values = (const float*)d_in[2];
    float* out = (float*)d_out;
    float* ws  = (float*)d_ws;

    const int nrows   = in_sizes[1] / DIM;
    const int nchunks = (nrows + 15) / 16;
    const int LN      = (nrows + 63) & ~63;          // logits region (floats)

    int P = 8192;                                    // waves in A and C
    const size_t capf = ws_size / sizeof(float);
    while ((size_t)LN + 16 + (size_t)(P + P / 64) * PSTRIDE > capf && P > 512)
        P >>= 1;
    const int B2 = P / 64;

    float*        logits  = ws;
    unsigned int* maxbits = (unsigned int*)(ws + LN);
    float*        part    = ws + LN + 16;
    float*        part2   = part + (size_t)P * PSTRIDE;

    hipMemsetAsync(maxbits, 0xFF, sizeof(unsigned int), stream);  // UINT_MAX seed
    nd_logits<<<P / 4, 256, 0, stream>>>(query, keys, logits, maxbits, nrows, nchunks, P);
    nd_accum <<<P / 4, 256, 0, stream>>>(values, logits, maxbits, part, nrows, nchunks, P);
    nd_merge <<<B2,    256, 0, stream>>>(part, part2);
    nd_final <<<1,     256, 0, stream>>>(part2, out, B2);
}

// Round 5
// 57.569 us; speedup vs baseline: 2.8235x; 2.8235x over previous
//
#include <hip/hip_runtime.h>
#include <math.h>

#define DIM 128
#define PSTRIDE 132          // per-partial floats: l, pad3, acc[128] (16B-aligned acc)
#define NEG_BIG (-3.0e38f)

// ---------------------------------------------------------------------------
// Phase A: logits. 4 lanes per row ("quad"), 16 rows per wave-chunk.
// Lane (quad,rsub) accumulates |k-q| over cols quad*4 + j*16 (8 independent
// float4 loads), 2 shfl_xor fold the quad. 2 chunks unrolled -> 16 loads in
// flight per lane. Per-wave max -> wsmax[wid] (NO global atomics).
// ---------------------------------------------------------------------------
__global__ __launch_bounds__(256) void nd_logits(const float* __restrict__ query,
                                                 const float* __restrict__ keys,
                                                 float* __restrict__ logits,
                                                 float* __restrict__ wsmax,
                                                 int nrows, int nchunks, int P) {
    const int tid  = threadIdx.x;
    const int lane = tid & 63;
    const int quad = lane & 3;
    const int rsub = lane >> 2;                       // 0..15
    const int wid  = blockIdx.x * (blockDim.x >> 6) + (tid >> 6);

    float4 qv[8];
    #pragma unroll
    for (int j = 0; j < 8; ++j)
        qv[j] = *reinterpret_cast<const float4*>(query + quad * 4 + j * 16);

    float wmax = NEG_BIG;

    #define PROC_CHUNK(cc)                                                        \
        {                                                                         \
            const int  row = (cc) * 16 + rsub;                                    \
            const bool ok  = row < nrows;                                         \
            const int  rr  = ok ? row : (nrows - 1);                              \
            const float* kp = keys + (size_t)rr * DIM + quad * 4;                 \
            float s = 0.f;                                                        \
            _Pragma("unroll")                                                     \
            for (int j = 0; j < 8; ++j) {                                         \
                const float4 k = *reinterpret_cast<const float4*>(kp + j * 16);   \
                s += fabsf(k.x - qv[j].x) + fabsf(k.y - qv[j].y)                  \
                   + fabsf(k.z - qv[j].z) + fabsf(k.w - qv[j].w);                 \
            }                                                                     \
            s += __shfl_xor(s, 1, 64);                                            \
            s += __shfl_xor(s, 2, 64);                                            \
            const float lg = ok ? -s : NEG_BIG;                                   \
            wmax = fmaxf(wmax, lg);                                               \
            if (quad == 0 && ok) logits[row] = lg;                                \
        }

    int c = wid;
    for (; c + P < nchunks; c += 2 * P) {
        PROC_CHUNK(c)
        PROC_CHUNK(c + P)
    }
    if (c < nchunks) PROC_CHUNK(c)
    #undef PROC_CHUNK

    #pragma unroll
    for (int off = 1; off < 64; off <<= 1)
        wmax = fmaxf(wmax, __shfl_xor(wmax, off, 64));
    if (lane == 0) wsmax[wid] = wmax;
}

// ---------------------------------------------------------------------------
// Phase B: reduce the P per-wave maxima to one float (single block, exact max
// -> order-independent -> deterministic).
// ---------------------------------------------------------------------------
__global__ __launch_bounds__(256) void nd_maxred(const float* __restrict__ wsmax,
                                                 float* __restrict__ maxval, int P) {
    __shared__ float sh[4];
    const int tid = threadIdx.x;
    float m = NEG_BIG;
    for (int i = tid; i < P; i += 256) m = fmaxf(m, wsmax[i]);
    #pragma unroll
    for (int off = 1; off < 64; off <<= 1)
        m = fmaxf(m, __shfl_xor(m, off, 64));
    if ((tid & 63) == 0) sh[tid >> 6] = m;
    __syncthreads();
    if (tid == 0)
        maxval[0] = fmaxf(fmaxf(sh[0], sh[1]), fmaxf(sh[2], sh[3]));
}

// ---------------------------------------------------------------------------
// Phase C: weighted value accumulation with FIXED global max M. Same quad
// layout; lane accumulates acc[8] (its 32 cols) with w = exp(logit-M).
// 2 chunks unrolled. End-of-kernel reduce over rsub (off 4..32).
// ---------------------------------------------------------------------------
__global__ __launch_bounds__(256) void nd_accum(const float* __restrict__ values,
                                                const float* __restrict__ logits,
                                                const float* __restrict__ maxval,
                                                float* __restrict__ part,
                                                int nrows, int nchunks, int P) {
    const int tid  = threadIdx.x;
    const int lane = tid & 63;
    const int quad = lane & 3;
    const int rsub = lane >> 2;
    const int wid  = blockIdx.x * (blockDim.x >> 6) + (tid >> 6);

    const float M = maxval[0];

    float4 acc[8];
    #pragma unroll
    for (int j = 0; j < 8; ++j) acc[j] = make_float4(0.f, 0.f, 0.f, 0.f);
    float l = 0.f;

    #define PROC_CHUNK(cc)                                                        \
        {                                                                         \
            const int  row = (cc) * 16 + rsub;                                    \
            const bool ok  = row < nrows;                                         \
            const int  rr  = ok ? row : (nrows - 1);                              \
            const float w  = ok ? __expf(logits[rr] - M) : 0.f;                   \
            const float* vp = values + (size_t)rr * DIM + quad * 4;               \
            l += w;                                                               \
            _Pragma("unroll")                                                     \
            for (int j = 0; j < 8; ++j) {                                         \
                const float4 v = *reinterpret_cast<const float4*>(vp + j * 16);   \
                acc[j].x += w * v.x; acc[j].y += w * v.y;                         \
                acc[j].z += w * v.z; acc[j].w += w * v.w;                         \
            }                                                                     \
        }

    int c = wid;
    for (; c + P < nchunks; c += 2 * P) {
        PROC_CHUNK(c)
        PROC_CHUNK(c + P)
    }
    if (c < nchunks) PROC_CHUNK(c)
    #undef PROC_CHUNK

    // Reduce over rsub (quad fixed): each col summed over all 16 row-subslots.
    #pragma unroll
    for (int off = 4; off < 64; off <<= 1) {
        #pragma unroll
        for (int j = 0; j < 8; ++j) {
            acc[j].x += __shfl_xor(acc[j].x, off, 64);
            acc[j].y += __shfl_xor(acc[j].y, off, 64);
            acc[j].z += __shfl_xor(acc[j].z, off, 64);
            acc[j].w += __shfl_xor(acc[j].w, off, 64);
        }
        l += __shfl_xor(l, off, 64);   // each row counted once per quad
    }

    if (rsub == 0) {                   // lanes 0..3 hold the wave's 128-col partial
        float* wp = part + (size_t)wid * PSTRIDE;
        if (quad == 0) wp[0] = l;
        #pragma unroll
        for (int j = 0; j < 8; ++j)
            *reinterpret_cast<float4*>(wp + 4 + quad * 4 + j * 16) = acc[j];
    }
}

// ---------------------------------------------------------------------------
// Merge 64 consecutive partials into one (plain sums).
// ---------------------------------------------------------------------------
__global__ __launch_bounds__(256) void nd_merge(const float* __restrict__ part,
                                                float* __restrict__ part2) {
    __shared__ float sh_red[256];
    __shared__ float shL;
    const int tid  = threadIdx.x;
    const int base = blockIdx.x * 64;

    if (tid < 64) {
        float lp = part[(size_t)(base + tid) * PSTRIDE];
        #pragma unroll
        for (int off = 32; off > 0; off >>= 1)
            lp += __shfl_xor(lp, off, 64);
        if (tid == 0) shL = lp;
    }

    const int d = tid & 127, g = tid >> 7;
    float o = 0.f;
    for (int p = g; p < 64; p += 2)
        o += part[(size_t)(base + p) * PSTRIDE + 4 + d];
    sh_red[tid] = o;
    __syncthreads();

    if (tid < 128) {
        float* wp = part2 + (size_t)blockIdx.x * PSTRIDE;
        if (tid == 0) wp[0] = shL;
        wp[4 + tid] = sh_red[tid] + sh_red[tid + 128];
    }
}

// ---------------------------------------------------------------------------
// Final: sum the B2 level-2 partials, normalize, write out[128].
// ---------------------------------------------------------------------------
__global__ __launch_bounds__(256) void nd_final(const float* __restrict__ part2,
                                                float* __restrict__ out, int B2) {
    __shared__ float sh_red[256];
    __shared__ float shL;
    const int tid = threadIdx.x;

    if (tid < 64) {
        float lp = 0.f;
        for (int p = tid; p < B2; p += 64)
            lp += part2[(size_t)p * PSTRIDE];
        #pragma unroll
        for (int off = 32; off > 0; off >>= 1)
            lp += __shfl_xor(lp, off, 64);
        if (tid == 0) shL = lp;
    }

    const int d = tid & 127, g = tid >> 7;
    float o = 0.f;
    for (int p = g; p < B2; p += 2)
        o += part2[(size_t)p * PSTRIDE + 4 + d];
    sh_red[tid] = o;
    __syncthreads();

    if (tid < 128)
        out[tid] = (sh_red[tid] + sh_red[tid + 128]) / shL;
}

extern "C" void kernel_launch(void* const* d_in, const int* in_sizes, int n_in,
                              void* d_out, int out_size, void* d_ws, size_t ws_size,
                              hipStream_t stream) {
    const float* query  = (const float*)d_in[0];
    const float* keys   = (const float*)d_in[1];
    const float* values = (const float*)d_in[2];
    float* out = (float*)d_out;
    float* ws  = (float*)d_ws;

    const int nrows   = in_sizes[1] / DIM;
    const int nchunks = (nrows + 15) / 16;
    const int LN      = (nrows + 63) & ~63;          // logits region (floats)

    int P = 2048;                                    // waves in A and C (~6 chunks/wave)
    const size_t capf = ws_size / sizeof(float);
    while ((size_t)LN + (size_t)P + 16 + (size_t)(P + P / 64) * PSTRIDE > capf && P > 512)
        P >>= 1;
    const int B2 = P / 64;

    float* logits = ws;
    float* wsmax  = ws + LN;
    float* maxval = wsmax + P;
    float* part   = maxval + 16;
    float* part2  = part + (size_t)P * PSTRIDE;

    nd_logits<<<P / 4, 256, 0, stream>>>(query, keys, logits, wsmax, nrows, nchunks, P);
    nd_maxred<<<1,     256, 0, stream>>>(wsmax, maxval, P);
    nd_accum <<<P / 4, 256, 0, stream>>>(values, logits, maxval, part, nrows, nchunks, P);
    nd_merge <<<B2,    256, 0, stream>>>(part, part2);
    nd_final <<<1,     256, 0, stream>>>(part2, out, B2);
}

// Round 6
// 54.050 us; speedup vs baseline: 3.0073x; 1.0651x over previous
//
#include <hip/hip_runtime.h>
#include <math.h>

#define DIM 128
#define PSTRIDE 132          // per-partial floats: m, l, pad2, acc[128] (16B-aligned acc)
#define NEG_BIG (-3.0e38f)

// ---------------------------------------------------------------------------
// Fused single pass. 4 lanes per row ("quad"), 16 rows per wave-chunk.
// Per chunk: lane loads its 32 key cols (8x float4) + 32 value cols, computes
// its row's L1 partial, 2 shfl_xor fold the quad -> EVERY lane holds its row's
// full logit. Then a PER-LANE online softmax (m, l, acc[8]x4) over the lane's
// private row stream -- no cross-lane carried state in the loop. At the end,
// lanes merge via the associative (m,l,acc) rule: wave max (6 shfl), rescale,
// sum over rsub (4 shfl rounds). One partial (m, l, acc[128]) per wave -> ws.
// ---------------------------------------------------------------------------
__global__ __launch_bounds__(256) void nd_fused(const float* __restrict__ query,
                                                const float* __restrict__ keys,
                                                const float* __restrict__ values,
                                                float* __restrict__ part,
                                                int nrows, int nchunks, int P) {
    const int tid  = threadIdx.x;
    const int lane = tid & 63;
    const int quad = lane & 3;
    const int rsub = lane >> 2;                       // 0..15
    const int wid  = blockIdx.x * (blockDim.x >> 6) + (tid >> 6);

    float4 qv[8];
    #pragma unroll
    for (int j = 0; j < 8; ++j)
        qv[j] = *reinterpret_cast<const float4*>(query + quad * 4 + j * 16);

    float  m = NEG_BIG;
    float  l = 0.f;
    float4 acc[8];
    #pragma unroll
    for (int j = 0; j < 8; ++j) acc[j] = make_float4(0.f, 0.f, 0.f, 0.f);

    for (int c = wid; c < nchunks; c += P) {
        const int  row = c * 16 + rsub;
        const bool ok  = row < nrows;
        const int  rr  = ok ? row : (nrows - 1);
        const float* kp = keys   + (size_t)rr * DIM + quad * 4;
        const float* vp = values + (size_t)rr * DIM + quad * 4;

        float4 kv[8], vv[8];
        #pragma unroll
        for (int j = 0; j < 8; ++j)
            kv[j] = *reinterpret_cast<const float4*>(kp + j * 16);
        #pragma unroll
        for (int j = 0; j < 8; ++j)
            vv[j] = *reinterpret_cast<const float4*>(vp + j * 16);

        float s = 0.f;
        #pragma unroll
        for (int j = 0; j < 8; ++j)
            s += fabsf(kv[j].x - qv[j].x) + fabsf(kv[j].y - qv[j].y)
               + fabsf(kv[j].z - qv[j].z) + fabsf(kv[j].w - qv[j].w);
        s += __shfl_xor(s, 1, 64);                    // fold quad: all 4 lanes
        s += __shfl_xor(s, 2, 64);                    // now hold the full logit
        const float lg = ok ? -s : NEG_BIG;

        const float newm  = fmaxf(m, lg);
        const float scale = __expf(m - newm);         // 0 on first valid chunk
        const float w     = ok ? __expf(lg - newm) : 0.f;
        l = l * scale + w;
        #pragma unroll
        for (int j = 0; j < 8; ++j) {
            acc[j].x = acc[j].x * scale + w * vv[j].x;
            acc[j].y = acc[j].y * scale + w * vv[j].y;
            acc[j].z = acc[j].z * scale + w * vv[j].z;
            acc[j].w = acc[j].w * scale + w * vv[j].w;
        }
        m = newm;
    }

    // Wave max (m is quad-uniform; reduce over all 64 lanes).
    float M = m;
    #pragma unroll
    for (int off = 1; off < 64; off <<= 1)
        M = fmaxf(M, __shfl_xor(M, off, 64));
    const float e = __expf(m - M);                    // m==NEG_BIG -> 0
    l *= e;
    #pragma unroll
    for (int j = 0; j < 8; ++j) {
        acc[j].x *= e; acc[j].y *= e; acc[j].z *= e; acc[j].w *= e;
    }

    // Sum over rsub (quad fixed): cols summed over the 16 row-streams.
    #pragma unroll
    for (int off = 4; off < 64; off <<= 1) {
        #pragma unroll
        for (int j = 0; j < 8; ++j) {
            acc[j].x += __shfl_xor(acc[j].x, off, 64);
            acc[j].y += __shfl_xor(acc[j].y, off, 64);
            acc[j].z += __shfl_xor(acc[j].z, off, 64);
            acc[j].w += __shfl_xor(acc[j].w, off, 64);
        }
        l += __shfl_xor(l, off, 64);   // each row counted once per quad lane
    }

    if (rsub == 0) {                   // lanes 0..3 hold the wave's 128-col partial
        float* wp = part + (size_t)wid * PSTRIDE;
        if (quad == 0) { wp[0] = M; wp[1] = l; }
        #pragma unroll
        for (int j = 0; j < 8; ++j)
            *reinterpret_cast<float4*>(wp + 4 + quad * 4 + j * 16) = acc[j];
    }
}

// ---------------------------------------------------------------------------
// Merge 64 consecutive partials into one with the max-aware rule:
//   M = max m_p; e_p = exp(m_p - M); l = sum l_p e_p; acc[d] = sum acc_p[d] e_p
// ---------------------------------------------------------------------------
__global__ __launch_bounds__(256) void nd_merge(const float* __restrict__ part,
                                                float* __restrict__ part2) {
    __shared__ float sh_e[64];
    __shared__ float sh_red[256];
    __shared__ float shM, shL;
    const int tid  = threadIdx.x;
    const int base = blockIdx.x * 64;

    if (tid < 64) {
        const float mm = part[(size_t)(base + tid) * PSTRIDE];
        float r = mm;
        #pragma unroll
        for (int off = 32; off > 0; off >>= 1)
            r = fmaxf(r, __shfl_xor(r, off, 64));
        const float e = __expf(mm - r);
        sh_e[tid] = e;
        float lp = part[(size_t)(base + tid) * PSTRIDE + 1] * e;
        #pragma unroll
        for (int off = 32; off > 0; off >>= 1)
            lp += __shfl_xor(lp, off, 64);
        if (tid == 0) { shM = r; shL = lp; }
    }
    __syncthreads();

    const int d = tid & 127, g = tid >> 7;
    float o = 0.f;
    for (int p = g; p < 64; p += 2)
        o += part[(size_t)(base + p) * PSTRIDE + 4 + d] * sh_e[p];
    sh_red[tid] = o;
    __syncthreads();

    if (tid < 128) {
        float* wp = part2 + (size_t)blockIdx.x * PSTRIDE;
        if (tid == 0) { wp[0] = shM; wp[1] = shL; }
        wp[4 + tid] = sh_red[tid] + sh_red[tid + 128];
    }
}

// ---------------------------------------------------------------------------
// Final: merge the B2 (<=128) level-2 partials, normalize, write out[128].
// ---------------------------------------------------------------------------
__global__ __launch_bounds__(256) void nd_final(const float* __restrict__ part2,
                                                float* __restrict__ out, int B2) {
    __shared__ float sh_e[128];
    __shared__ float sh_red[256];
    __shared__ float shL;
    const int tid = threadIdx.x;

    if (tid < 64) {
        const float m0 = (tid      < B2) ? part2[(size_t)tid * PSTRIDE]        : NEG_BIG;
        const float m1 = (tid + 64 < B2) ? part2[(size_t)(tid + 64) * PSTRIDE] : NEG_BIG;
        float r = fmaxf(m0, m1);
        #pragma unroll
        for (int off = 32; off > 0; off >>= 1)
            r = fmaxf(r, __shfl_xor(r, off, 64));
        const float e0 = (tid      < B2) ? __expf(m0 - r) : 0.f;
        const float e1 = (tid + 64 < B2) ? __expf(m1 - r) : 0.f;
        sh_e[tid] = e0; sh_e[tid + 64] = e1;
        float lp = 0.f;
        if (tid      < B2) lp += part2[(size_t)tid * PSTRIDE + 1] * e0;
        if (tid + 64 < B2) lp += part2[(size_t)(tid + 64) * PSTRIDE + 1] * e1;
        #pragma unroll
        for (int off = 32; off > 0; off >>= 1)
            lp += __shfl_xor(lp, off, 64);
        if (tid == 0) shL = lp;
    }
    __syncthreads();

    const int d = tid & 127, g = tid >> 7;
    float o = 0.f;
    for (int p = g; p < B2; p += 2)
        o += part2[(size_t)p * PSTRIDE + 4 + d] * sh_e[p];
    sh_red[tid] = o;
    __syncthreads();

    if (tid < 128)
        out[tid] = (sh_red[tid] + sh_red[tid + 128]) / shL;
}

extern "C" void kernel_launch(void* const* d_in, const int* in_sizes, int n_in,
                              void* d_out, int out_size, void* d_ws, size_t ws_size,
                              hipStream_t stream) {
    const float* query  = (const float*)d_in[0];
    const float* keys   = (const float*)d_in[1];
    const float* values = (const float*)d_in[2];
    float* out = (float*)d_out;
    float* ws  = (float*)d_ws;

    const int nrows   = in_sizes[1] / DIM;
    const int nchunks = (nrows + 15) / 16;

    int P = 2048;                                    // waves (512 blocks, ~6 chunks/wave)
    const size_t capf = ws_size / sizeof(float);
    while ((size_t)(P + P / 64) * PSTRIDE > capf && P > 512) P >>= 1;
    const int B2 = P / 64;

    float* part  = ws;
    float* part2 = part + (size_t)P * PSTRIDE;

    nd_fused<<<P / 4, 256, 0, stream>>>(query, keys, values, part, nrows, nchunks, P);
    nd_merge<<<B2,    256, 0, stream>>>(part, part2);
    nd_final<<<1,     256, 0, stream>>>(part2, out, B2);
}